// Round 1
// baseline (372.460 us; speedup 1.0000x reference)
//
#include <hip/hip_runtime.h>
#include <hip/hip_bf16.h>

#define NN 512
#define NI 64
#define NJ 16
#define DD 256
#define HI 64
#define HO 64

typedef unsigned int  u32;
typedef unsigned short u16;

__device__ __forceinline__ float gelu_exact(float x){
    return 0.5f * x * (1.0f + erff(x * 0.7071067811865476f));
}
__device__ __forceinline__ float sigm(float x){
    return 1.0f / (1.0f + __expf(-x));
}
__device__ __forceinline__ float us2f(u16 u){
    union { u32 ui; float f; } cv; cv.ui = ((u32)u) << 16; return cv.f;
}
__device__ __forceinline__ u16 f2us(float f){
    union { float f; u32 u; } cv; cv.f = f;
    u32 r = cv.u + 0x7FFFu + ((cv.u >> 16) & 1u);   // RNE
    return (u16)(r >> 16);
}

// ---------------- Kernel A: xc = gelu(x @ Wcap + Bcap) ----------------
// grid (8 nchunks, 64 i), block 256. 64x64 tile, K=256.
__global__ __launch_bounds__(256) void k_xc(const float* __restrict__ x,
    const float* __restrict__ Wcap, const float* __restrict__ Bcap,
    float* __restrict__ xc)
{
    __shared__ float a_l[64][65];   // x[n0+r][i][k0+c]
    __shared__ float b_l[64][68];   // Wcap[i][k0+r][c]
    const int n0 = blockIdx.x * 64;
    const int i  = blockIdx.y;
    const int t  = threadIdx.x;
    const int tr = t >> 4, tc = t & 15;
    float acc[4][4] = {};
    for (int k0 = 0; k0 < DD; k0 += 64){
        #pragma unroll
        for (int u = 0; u < 16; ++u){
            int idx = t + u * 256;
            int r = idx >> 6, c = idx & 63;
            a_l[r][c] = x[(size_t)(n0 + r) * (NI * DD) + (size_t)i * DD + k0 + c];
            b_l[r][c] = Wcap[(size_t)i * (DD * HI) + (size_t)(k0 + r) * HI + c];
        }
        __syncthreads();
        #pragma unroll 8
        for (int k = 0; k < 64; ++k){
            float av[4];
            #pragma unroll
            for (int q = 0; q < 4; ++q) av[q] = a_l[tr * 4 + q][k];
            float4 bv = *(const float4*)&b_l[k][tc * 4];
            #pragma unroll
            for (int q = 0; q < 4; ++q){
                acc[q][0] += av[q] * bv.x; acc[q][1] += av[q] * bv.y;
                acc[q][2] += av[q] * bv.z; acc[q][3] += av[q] * bv.w;
            }
        }
        __syncthreads();
    }
    #pragma unroll
    for (int q = 0; q < 4; ++q){
        int n = n0 + tr * 4 + q;
        #pragma unroll
        for (int p = 0; p < 4; ++p){
            int h = tc * 4 + p;
            float v = acc[q][p] + Bcap[i * HI + h];
            xc[(size_t)n * (NI * HI) + (size_t)i * HI + h] = gelu_exact(v);
        }
    }
}

// ------- Kernel B: votes (masked, bf16), fn_v (bf16), bij (fp32) -------
// grid (8 nchunks, 16 j, 64 i), block 256.
__global__ __launch_bounds__(256) void k_votes(
    const float* __restrict__ xc, const float* __restrict__ Wv,
    const float* __restrict__ Bv, const float* __restrict__ mask,
    const float* __restrict__ fn1W, const float* __restrict__ fn1b,
    const float* __restrict__ scoreW, const float* __restrict__ scoreb,
    u16* __restrict__ votes, u16* __restrict__ fnv, float* __restrict__ bij)
{
    __shared__ float a_l[64][65];   // xc tile, later fn_v staging
    __shared__ float b_l[64][68];   // Wv[i][j] then fn1W
    __shared__ float v_l[64][68];   // masked votes tile (fp32)
    const int n0 = blockIdx.x * 64;
    const int j  = blockIdx.y;
    const int i  = blockIdx.z;
    const int t  = threadIdx.x;
    const int tr = t >> 4, tc = t & 15;

    #pragma unroll
    for (int u = 0; u < 16; ++u){
        int idx = t + u * 256;
        int r = idx >> 6, c = idx & 63;
        a_l[r][c] = xc[(size_t)(n0 + r) * (NI * HI) + (size_t)i * HI + c];
        b_l[r][c] = Wv[((size_t)(i * NJ + j) * HI + r) * HO + c];
    }
    __syncthreads();

    float acc[4][4] = {};
    #pragma unroll 8
    for (int k = 0; k < 64; ++k){
        float av[4];
        #pragma unroll
        for (int q = 0; q < 4; ++q) av[q] = a_l[tr * 4 + q][k];
        float4 bv = *(const float4*)&b_l[k][tc * 4];
        #pragma unroll
        for (int q = 0; q < 4; ++q){
            acc[q][0] += av[q] * bv.x; acc[q][1] += av[q] * bv.y;
            acc[q][2] += av[q] * bv.z; acc[q][3] += av[q] * bv.w;
        }
    }
    __syncthreads();

    // masked votes -> v_l; stage fn1W into b_l
    float mkv[4];
    #pragma unroll
    for (int q = 0; q < 4; ++q) mkv[q] = mask[(size_t)(n0 + tr * 4 + q) * NI + i];
    #pragma unroll
    for (int q = 0; q < 4; ++q){
        #pragma unroll
        for (int p = 0; p < 4; ++p){
            int h = tc * 4 + p;
            v_l[tr * 4 + q][h] = (acc[q][p] + Bv[(size_t)(i * NJ + j) * HO + h]) * mkv[q];
        }
    }
    #pragma unroll
    for (int u = 0; u < 16; ++u){
        int idx = t + u * 256;
        b_l[idx >> 6][idx & 63] = fn1W[idx];
    }
    __syncthreads();

    // votes writeout (bf16, vectorized)
    {
        int r = t >> 2, c0 = (t & 3) * 16;
        u32 pk[8];
        #pragma unroll
        for (int e = 0; e < 8; ++e){
            u32 lo = f2us(v_l[r][c0 + 2 * e]);
            u32 hi = f2us(v_l[r][c0 + 2 * e + 1]);
            pk[e] = lo | (hi << 16);
        }
        size_t off = ((size_t)(n0 + r) * NJ + j) * (size_t)(NI * HO) + (size_t)i * HO + c0;
        uint4* dst = (uint4*)(votes + off);
        dst[0] = make_uint4(pk[0], pk[1], pk[2], pk[3]);
        dst[1] = make_uint4(pk[4], pk[5], pk[6], pk[7]);
    }

    // fn_v = v_l @ fn1W^T  (thread cols h = tc + 16p to stay conflict-free)
    float acc2[4][4] = {};
    #pragma unroll
    for (int c0 = 0; c0 < 64; c0 += 4){
        float4 vv[4], ww[4];
        #pragma unroll
        for (int q = 0; q < 4; ++q) vv[q] = *(const float4*)&v_l[tr * 4 + q][c0];
        #pragma unroll
        for (int p = 0; p < 4; ++p) ww[p] = *(const float4*)&b_l[tc + 16 * p][c0];
        #pragma unroll
        for (int q = 0; q < 4; ++q){
            #pragma unroll
            for (int p = 0; p < 4; ++p){
                acc2[q][p] += vv[q].x * ww[p].x + vv[q].y * ww[p].y
                            + vv[q].z * ww[p].z + vv[q].w * ww[p].w;
            }
        }
    }
    #pragma unroll
    for (int q = 0; q < 4; ++q){
        #pragma unroll
        for (int p = 0; p < 4; ++p){
            int h = tc + 16 * p;
            a_l[tr * 4 + q][h] = acc2[q][p] + fn1b[h];
        }
    }
    __syncthreads();

    // fn_v writeout + bij
    {
        int r = t >> 2, c0 = (t & 3) * 16;
        u32 pk[8];
        #pragma unroll
        for (int e = 0; e < 8; ++e){
            u32 lo = f2us(a_l[r][c0 + 2 * e]);
            u32 hi = f2us(a_l[r][c0 + 2 * e + 1]);
            pk[e] = lo | (hi << 16);
        }
        size_t off = ((size_t)(n0 + r) * NJ + j) * (size_t)(NI * HO) + (size_t)i * HO + c0;
        uint4* dst = (uint4*)(fnv + off);
        dst[0] = make_uint4(pk[0], pk[1], pk[2], pk[3]);
        dst[1] = make_uint4(pk[4], pk[5], pk[6], pk[7]);
    }
    if (t < 64){
        float s = 0.f;
        #pragma unroll
        for (int c0 = 0; c0 < 64; c0 += 4){
            float4 v4 = *(const float4*)&v_l[t][c0];
            s += v4.x * scoreW[c0] + v4.y * scoreW[c0 + 1]
               + v4.z * scoreW[c0 + 2] + v4.w * scoreW[c0 + 3];
        }
        bij[((size_t)(n0 + t) * NJ + j) * NI + i] = s + scoreb[0];
    }
}

// ---------------- Kernel C: softmax + routing iterations ----------------
// grid 8192 = (n,j), block 128 (2 waves).
__global__ __launch_bounds__(128) void k_route(
    const u16* __restrict__ votes, const u16* __restrict__ fnv,
    const float* __restrict__ bijg, const float* __restrict__ mask,
    const float* __restrict__ alphaW, const float* __restrict__ alphab,
    const float* __restrict__ fe1W, const float* __restrict__ fe1b,
    const float* __restrict__ fe2W, const float* __restrict__ fe2b,
    const float* __restrict__ fn2W, const float* __restrict__ fn2b,
    const int* __restrict__ itersp, float* __restrict__ out)
{
    __shared__ u16 v_l[64][66];
    __shared__ u16 f_l[64][66];
    __shared__ float wA[64][65];   // fe2W
    __shared__ float wB[64][65];   // fn2W
    __shared__ float wC[64][65];   // fe1W
    __shared__ float s_aij[64], s_vj[64], s_g[64], s_u[64], s_w[64], s_M[64];
    __shared__ float s_part[2][64];
    __shared__ float s_scal[2];

    const int bid = blockIdx.x;
    const int n = bid >> 4;
    const int j = bid & 15;
    const int t = threadIdx.x;
    const int lane = t & 63;
    const int wv = t >> 6;

    const u32* vsrc = (const u32*)(votes + ((size_t)(n * NJ + j) << 12));
    const u32* fsrc = (const u32*)(fnv   + ((size_t)(n * NJ + j) << 12));
    #pragma unroll
    for (int u = 0; u < 16; ++u){
        int wid = t + u * 128;               // 0..2047
        int row = wid >> 5, c2 = (wid & 31) << 1;
        *(u32*)&v_l[row][c2] = vsrc[wid];
        *(u32*)&f_l[row][c2] = fsrc[wid];
    }
    #pragma unroll
    for (int u = 0; u < 32; ++u){
        int idx = t + u * 128;               // 0..4095
        int r = idx >> 6, c = idx & 63;
        wA[r][c] = fe2W[idx];
        wB[r][c] = fn2W[idx];
        wC[r][c] = fe1W[idx];
    }

    const float mki  = mask[(size_t)n * NI + lane];
    const float atti = (mki == 0.f) ? -3.0e38f : 0.f;

    if (wv == 0){
        float b = bijg[((size_t)n * NJ + j) * NI + lane];
        float s = b * mki + atti;
        float mx = s;
        #pragma unroll
        for (int off = 32; off; off >>= 1) mx = fmaxf(mx, __shfl_xor(mx, off));
        float p = __expf(s - mx);
        float sm = p;
        #pragma unroll
        for (int off = 32; off; off >>= 1) sm += __shfl_xor(sm, off);
        s_aij[lane] = p / sm;
    }
    __syncthreads();

    const int iters = itersp[0];
    for (int it = 0; it < iters; ++it){
        // nv[h] = sum_i aij[i] * votes[i][h]   (i split across the 2 waves)
        {
            float part = 0.f;
            int i0 = wv << 5;
            #pragma unroll 8
            for (int ii = 0; ii < 32; ++ii)
                part += s_aij[i0 + ii] * us2f(v_l[i0 + ii][lane]);
            s_part[wv][lane] = part;
        }
        __syncthreads();
        if (wv == 0){
            float nv = gelu_exact(s_part[0][lane] + s_part[1][lane]);
            if (it == 0){
                s_vj[lane] = nv;
            } else {
                float dv = nv * alphaW[lane];
                #pragma unroll
                for (int off = 32; off; off >>= 1) dv += __shfl_xor(dv, off);
                float alpha = sigm(dv + alphab[0]);
                s_vj[lane] = alpha * nv + (1.f - alpha) * s_vj[lane];
            }
        }
        __syncthreads();
        if (it == iters - 1) break;

        // g = fe2(vj) (wave0), w = fn2(vj) (wave1)
        if (wv == 0){
            float a = fe2b[lane];
            #pragma unroll 8
            for (int h = 0; h < 64; ++h) a += wA[lane][h] * s_vj[h];
            s_g[lane] = a;
        } else {
            float a = fn2b[lane];
            #pragma unroll 8
            for (int h = 0; h < 64; ++h) a += wB[lane][h] * s_vj[h];
            s_w[lane] = a;
        }
        __syncthreads();

        // wave0: u = fe1W^T g, c = fe1b.g ;  wave1: M[i]
        if (wv == 0){
            float a = 0.f;
            #pragma unroll 8
            for (int h = 0; h < 64; ++h) a += wC[h][lane] * s_g[h];
            s_u[lane] = a;
            float cv = fe1b[lane] * s_g[lane];
            #pragma unroll
            for (int off = 32; off; off >>= 1) cv += __shfl_xor(cv, off);
            if (lane == 0) s_scal[0] = cv;
        } else {
            float a = 0.f;
            const u32* frow = (const u32*)&f_l[lane][0];
            #pragma unroll 8
            for (int h2 = 0; h2 < 32; ++h2){
                u32 u = frow[h2];
                a += fabsf(us2f((u16)(u & 0xffff)) - s_w[2 * h2])
                   + fabsf(us2f((u16)(u >> 16))    - s_w[2 * h2 + 1]);
            }
            s_M[lane] = -a;
        }
        __syncthreads();

        if (wv == 0){
            float e = s_scal[0];
            const u32* vrow = (const u32*)&v_l[lane][0];
            #pragma unroll 8
            for (int h2 = 0; h2 < 32; ++h2){
                u32 u = vrow[h2];
                e += us2f((u16)(u & 0xffff)) * s_u[2 * h2]
                   + us2f((u16)(u >> 16))    * s_u[2 * h2 + 1];
            }
            s_aij[lane] = tanhf(e) * sigm(s_M[lane] * mki + atti);
        }
        __syncthreads();
    }

    if (wv == 0)
        out[((size_t)n * NJ + j) * HO + lane] = s_vj[lane];
}

extern "C" void kernel_launch(void* const* d_in, const int* in_sizes, int n_in,
                              void* d_out, int out_size, void* d_ws, size_t ws_size,
                              hipStream_t stream)
{
    (void)in_sizes; (void)n_in; (void)out_size; (void)ws_size;
    const float* x      = (const float*)d_in[0];
    const float* mask   = (const float*)d_in[1];
    const float* Wcap   = (const float*)d_in[2];
    const float* Bcap   = (const float*)d_in[3];
    const float* Wv     = (const float*)d_in[4];
    const float* Bv     = (const float*)d_in[5];
    const float* scoreW = (const float*)d_in[6];
    const float* scoreb = (const float*)d_in[7];
    const float* alphaW = (const float*)d_in[8];
    const float* alphab = (const float*)d_in[9];
    const float* fe1W   = (const float*)d_in[10];
    const float* fe1b   = (const float*)d_in[11];
    const float* fe2W   = (const float*)d_in[12];
    const float* fe2b   = (const float*)d_in[13];
    const float* fn1W   = (const float*)d_in[14];
    const float* fn1b   = (const float*)d_in[15];
    const float* fn2W   = (const float*)d_in[16];
    const float* fn2b   = (const float*)d_in[17];
    const int*   itersp = (const int*)d_in[18];
    float* out = (float*)d_out;

    char* ws = (char*)d_ws;
    float* xc   = (float*)ws;                         //   8,388,608 B
    u16*   vts  = (u16*)(ws + 8388608);               //  67,108,864 B
    u16*   fnv  = (u16*)(ws + 75497472);              //  67,108,864 B
    float* bij  = (float*)(ws + 142606336);           //   2,097,152 B  (total 138 MB)

    k_xc   <<<dim3(8, 64),      256, 0, stream>>>(x, Wcap, Bcap, xc);
    k_votes<<<dim3(8, 16, 64),  256, 0, stream>>>(xc, Wv, Bv, mask, fn1W, fn1b,
                                                  scoreW, scoreb, vts, fnv, bij);
    k_route<<<dim3(8192),       128, 0, stream>>>(vts, fnv, bij, mask, alphaW, alphab,
                                                  fe1W, fe1b, fe2W, fe2b, fn2W, fn2b,
                                                  itersp, out);
}

// Round 2
// 214.011 us; speedup vs baseline: 1.7404x; 1.7404x over previous
//
#include <hip/hip_runtime.h>
#include <hip/hip_bf16.h>

#define NN 512
#define NI 64
#define NJ 16
#define DD 256
#define HI 64
#define HO 64

typedef unsigned int  u32;
typedef unsigned short u16;

typedef __attribute__((ext_vector_type(8))) short bf16x8;
typedef __attribute__((ext_vector_type(4))) float f32x4;

__device__ __forceinline__ float gelu_exact(float x){
    return 0.5f * x * (1.0f + erff(x * 0.7071067811865476f));
}
__device__ __forceinline__ float sigm(float x){
    return 1.0f / (1.0f + __expf(-x));
}
__device__ __forceinline__ float us2f(u16 u){
    union { u32 ui; float f; } cv; cv.ui = ((u32)u) << 16; return cv.f;
}
__device__ __forceinline__ float bflo(u32 x){
    union { u32 u; float f; } c; c.u = x << 16; return c.f;
}
__device__ __forceinline__ float bfhi(u32 x){
    union { u32 u; float f; } c; c.u = x & 0xffff0000u; return c.f;
}
__device__ __forceinline__ u16 f2us(float f){
    union { float f; u32 u; } cv; cv.f = f;
    u32 r = cv.u + 0x7FFFu + ((cv.u >> 16) & 1u);   // RNE
    return (u16)(r >> 16);
}
__device__ __forceinline__ float dot8(uint4 q, const float* v){
    return bflo(q.x) * v[0] + bfhi(q.x) * v[1]
         + bflo(q.y) * v[2] + bfhi(q.y) * v[3]
         + bflo(q.z) * v[4] + bfhi(q.z) * v[5]
         + bflo(q.w) * v[6] + bfhi(q.w) * v[7];
}

// ------------- prep: small weights -> bf16 (fe1W transposed) -------------
__global__ __launch_bounds__(256) void k_prep_small(
    const float* __restrict__ fn1W, const float* __restrict__ fe2W,
    const float* __restrict__ fn2W, const float* __restrict__ fe1W,
    u16* __restrict__ fn1wb, u16* __restrict__ wAb,
    u16* __restrict__ wBb, u16* __restrict__ wCtb)
{
    const int t = threadIdx.x;
    #pragma unroll
    for (int u = 0; u < 16; ++u){
        int idx = t + u * 256;
        fn1wb[idx] = f2us(fn1W[idx]);
        wAb[idx]   = f2us(fe2W[idx]);
        wBb[idx]   = f2us(fn2W[idx]);
        int n = idx >> 6, h = idx & 63;
        wCtb[idx]  = f2us(fe1W[h * 64 + n]);   // wCt[n][h] = fe1W[h][n]
    }
}

// ---------------- Kernel A: xc = gelu(x @ Wcap + Bcap), bf16 out ----------------
__global__ __launch_bounds__(256) void k_xc(const float* __restrict__ x,
    const float* __restrict__ Wcap, const float* __restrict__ Bcap,
    u16* __restrict__ xcb)
{
    __shared__ float a_l[64][65];
    __shared__ float b_l[64][68];
    const int n0 = blockIdx.x * 64;
    const int i  = blockIdx.y;
    const int t  = threadIdx.x;
    const int tr = t >> 4, tc = t & 15;
    float acc[4][4] = {};
    for (int k0 = 0; k0 < DD; k0 += 64){
        #pragma unroll
        for (int u = 0; u < 16; ++u){
            int idx = t + u * 256;
            int r = idx >> 6, c = idx & 63;
            a_l[r][c] = x[(size_t)(n0 + r) * (NI * DD) + (size_t)i * DD + k0 + c];
            b_l[r][c] = Wcap[(size_t)i * (DD * HI) + (size_t)(k0 + r) * HI + c];
        }
        __syncthreads();
        #pragma unroll 8
        for (int k = 0; k < 64; ++k){
            float av[4];
            #pragma unroll
            for (int q = 0; q < 4; ++q) av[q] = a_l[tr * 4 + q][k];
            float4 bv = *(const float4*)&b_l[k][tc * 4];
            #pragma unroll
            for (int q = 0; q < 4; ++q){
                acc[q][0] += av[q] * bv.x; acc[q][1] += av[q] * bv.y;
                acc[q][2] += av[q] * bv.z; acc[q][3] += av[q] * bv.w;
            }
        }
        __syncthreads();
    }
    #pragma unroll
    for (int q = 0; q < 4; ++q){
        int n = n0 + tr * 4 + q;
        float vv[4];
        #pragma unroll
        for (int p = 0; p < 4; ++p)
            vv[p] = gelu_exact(acc[q][p] + Bcap[i * HI + tc * 4 + p]);
        u32 p0 = (u32)f2us(vv[0]) | ((u32)f2us(vv[1]) << 16);
        u32 p1 = (u32)f2us(vv[2]) | ((u32)f2us(vv[3]) << 16);
        *(uint2*)&xcb[((size_t)n * NI + i) * HI + tc * 4] = make_uint2(p0, p1);
    }
}

// ------- Kernel B: MFMA votes (masked, bf16), fn_v (bf16), bij (fp32) -------
// grid (8 nchunks, 16 j, 64 i), block 256 (4 waves, each a 16-row strip).
__global__ __launch_bounds__(256) void k_votes(
    const u16* __restrict__ xcb, const float* __restrict__ Wv,
    const float* __restrict__ Bv, const float* __restrict__ mask,
    const u16* __restrict__ fn1wb, const float* __restrict__ fn1b,
    const float* __restrict__ scoreW, const float* __restrict__ scoreb,
    u16* __restrict__ votes, u16* __restrict__ fnv, float* __restrict__ bij)
{
    __shared__ u16 w_l[64][72];   // Wv[i][j] transposed: [h][k] bf16
    __shared__ u16 v_l[64][72];   // masked votes [n][h] bf16
    __shared__ u16 f_l[64][72];   // fn_v [n][h] bf16
    const int n0 = blockIdx.x * 64;
    const int j  = blockIdx.y;
    const int i  = blockIdx.z;
    const int t  = threadIdx.x;
    const int w  = t >> 6;        // wave -> rows [16w,16w+16)
    const int l  = t & 63;
    const int lr = l & 15;        // row/col index within 16x16 tile
    const int lg = l >> 4;        // k-group

    // stage Wv tile (fp32 [k][h]) -> w_l[h][k] bf16
    const float* wsrc = Wv + (size_t)(i * NJ + j) * 4096;
    #pragma unroll
    for (int u = 0; u < 16; ++u){
        int idx = t + u * 256;            // = k*64 + h
        int k = idx >> 6, h = idx & 63;
        w_l[h][k] = f2us(wsrc[idx]);
    }
    __syncthreads();

    // A fragments from global xcb (16B per lane, k-halves)
    const u16* arow = xcb + ((size_t)(n0 + 16 * w + lr) * NI + i) * HI + lg * 8;
    bf16x8 a0 = *(const bf16x8*)(arow);
    bf16x8 a1 = *(const bf16x8*)(arow + 32);

    f32x4 acc[4];
    #pragma unroll
    for (int ht = 0; ht < 4; ++ht){
        const u16* brow = &w_l[ht * 16 + lr][lg * 8];
        bf16x8 b0 = *(const bf16x8*)(brow);
        bf16x8 b1 = *(const bf16x8*)(brow + 32);
        f32x4 c = {};
        c = __builtin_amdgcn_mfma_f32_16x16x32_bf16(a0, b0, c, 0, 0, 0);
        c = __builtin_amdgcn_mfma_f32_16x16x32_bf16(a1, b1, c, 0, 0, 0);
        acc[ht] = c;
    }

    // mask + bias -> v_l (bf16); bij partials in registers
    const float* bvp = Bv + (size_t)(i * NJ + j) * HO;
    float mk[4];
    #pragma unroll
    for (int r = 0; r < 4; ++r)
        mk[r] = mask[(size_t)(n0 + 16 * w + lg * 4 + r) * NI + i];
    float p[4] = {0.f, 0.f, 0.f, 0.f};
    #pragma unroll
    for (int ht = 0; ht < 4; ++ht){
        int h = ht * 16 + lr;
        float bv = bvp[h];
        float sw = scoreW[h];
        #pragma unroll
        for (int r = 0; r < 4; ++r){
            float val = (acc[ht][r] + bv) * mk[r];
            v_l[16 * w + lg * 4 + r][h] = f2us(val);
            p[r] += val * sw;
        }
    }
    // bij: reduce across the 16 lanes of each column-group
    #pragma unroll
    for (int r = 0; r < 4; ++r){
        float s = p[r];
        #pragma unroll
        for (int off = 1; off < 16; off <<= 1) s += __shfl_xor(s, off);
        if (lr == 0){
            int n = n0 + 16 * w + lg * 4 + r;
            bij[((size_t)n * NJ + j) * NI + i] = s + scoreb[0];
        }
    }

    // fn_v = votes @ fn1W^T  (A from v_l — own strip, written by this wave)
    const u16* var = &v_l[16 * w + lr][lg * 8];
    bf16x8 fa0 = *(const bf16x8*)(var);
    bf16x8 fa1 = *(const bf16x8*)(var + 32);
    #pragma unroll
    for (int nt = 0; nt < 4; ++nt){
        const u16* brow = fn1wb + (nt * 16 + lr) * 64 + lg * 8;
        bf16x8 b0 = *(const bf16x8*)(brow);
        bf16x8 b1 = *(const bf16x8*)(brow + 32);
        f32x4 c = {};
        c = __builtin_amdgcn_mfma_f32_16x16x32_bf16(fa0, b0, c, 0, 0, 0);
        c = __builtin_amdgcn_mfma_f32_16x16x32_bf16(fa1, b1, c, 0, 0, 0);
        int hn = nt * 16 + lr;
        float fb = fn1b[hn];
        #pragma unroll
        for (int r = 0; r < 4; ++r)
            f_l[16 * w + lg * 4 + r][hn] = f2us(c[r] + fb);
    }
    __syncthreads();

    // coalesced global writes of both tiles
    {
        int row = t >> 2, c0 = (t & 3) * 16;
        size_t off = ((size_t)(n0 + row) * NJ + j) * (size_t)(NI * HO)
                   + (size_t)i * HO + c0;
        uint4 q0 = *(const uint4*)&v_l[row][c0];
        uint4 q1 = *(const uint4*)&v_l[row][c0 + 8];
        *(uint4*)(votes + off)     = q0;
        *(uint4*)(votes + off + 8) = q1;
        uint4 r0 = *(const uint4*)&f_l[row][c0];
        uint4 r1 = *(const uint4*)&f_l[row][c0 + 8];
        *(uint4*)(fnv + off)       = r0;
        *(uint4*)(fnv + off + 8)   = r1;
    }
}

// ---------------- Kernel C: softmax + routing iterations ----------------
// grid 8192 = (n,j), block 128 (2 waves). LDS ~11 KB.
__global__ __launch_bounds__(128) void k_route(
    const u16* __restrict__ votes, const u16* __restrict__ fnv,
    const float* __restrict__ bijg, const float* __restrict__ mask,
    const float* __restrict__ alphaW, const float* __restrict__ alphab,
    const u16* __restrict__ wAb, const float* __restrict__ fe2b,
    const u16* __restrict__ wBb, const float* __restrict__ fn2b,
    const u16* __restrict__ wCtb, const float* __restrict__ fe1b,
    const int* __restrict__ itersp, float* __restrict__ out)
{
    __shared__ u16 v_l[64][72];
    __shared__ float s_aij[64], s_vj[64], s_g[64], s_u[64], s_w[64], s_M[64];
    __shared__ float s_part[2][64];
    __shared__ float s_scal;

    const int bid = blockIdx.x;
    const int n = bid >> 4;
    const int j = bid & 15;
    const int t = threadIdx.x;
    const int lane = t & 63;
    const int wv = t >> 6;
    const size_t base = ((size_t)n * NJ + j) * (size_t)(NI * HO);

    // wave0: votes row `lane` -> regs + LDS.  wave1: fnv row `lane` -> regs.
    uint4 dr[8];
    if (wv == 0){
        const uint4* vp = (const uint4*)(votes + base + (size_t)lane * HO);
        #pragma unroll
        for (int c = 0; c < 8; ++c) dr[c] = vp[c];
        #pragma unroll
        for (int c = 0; c < 8; ++c) *(uint4*)&v_l[lane][c * 8] = dr[c];
    } else {
        const uint4* fp = (const uint4*)(fnv + base + (size_t)lane * HO);
        #pragma unroll
        for (int c = 0; c < 8; ++c) dr[c] = fp[c];
    }

    const float mki  = mask[(size_t)n * NI + lane];
    const float atti = (mki == 0.f) ? -3.0e38f : 0.f;

    if (wv == 0){
        float b = bijg[((size_t)n * NJ + j) * NI + lane];
        float s = b * mki + atti;
        float mx = s;
        #pragma unroll
        for (int off = 32; off; off >>= 1) mx = fmaxf(mx, __shfl_xor(mx, off));
        float p = __expf(s - mx);
        float sm = p;
        #pragma unroll
        for (int off = 32; off; off >>= 1) sm += __shfl_xor(sm, off);
        s_aij[lane] = p / sm;
    }
    __syncthreads();

    const int iters = itersp[0];
    for (int it = 0; it < iters; ++it){
        // nv[h] = sum_i aij[i]*votes[i][h], i split across the 2 waves
        {
            float part = 0.f;
            int i0 = wv << 5;
            #pragma unroll 8
            for (int ii = 0; ii < 32; ++ii)
                part += s_aij[i0 + ii] * us2f(v_l[i0 + ii][lane]);
            s_part[wv][lane] = part;
        }
        __syncthreads();
        if (wv == 0){
            float nv = gelu_exact(s_part[0][lane] + s_part[1][lane]);
            if (it == 0){
                s_vj[lane] = nv;
            } else {
                float dv = nv * alphaW[lane];
                #pragma unroll
                for (int off = 32; off; off >>= 1) dv += __shfl_xor(dv, off);
                float alpha = sigm(dv + alphab[0]);
                s_vj[lane] = alpha * nv + (1.f - alpha) * s_vj[lane];
            }
        }
        __syncthreads();
        if (it == iters - 1) break;

        if (wv == 0){
            // g = fe2(vj); then u = fe1W^T g, scal = fe1b . g  (same-wave LDS deps)
            float a = 0.f;
            const uint4* wr = (const uint4*)(wAb + lane * 64);
            #pragma unroll
            for (int c = 0; c < 8; ++c) a += dot8(wr[c], &s_vj[c * 8]);
            s_g[lane] = a + fe2b[lane];

            float ua = 0.f;
            const uint4* wc = (const uint4*)(wCtb + lane * 64);
            #pragma unroll
            for (int c = 0; c < 8; ++c) ua += dot8(wc[c], &s_g[c * 8]);
            s_u[lane] = ua;
            float cv = fe1b[lane] * s_g[lane];
            #pragma unroll
            for (int off = 32; off; off >>= 1) cv += __shfl_xor(cv, off);
            if (lane == 0) s_scal = cv;
        } else {
            // w = fn2(vj); then M[i] = -sum_h |fnv[i][h] - w[h]|
            float a = 0.f;
            const uint4* wr = (const uint4*)(wBb + lane * 64);
            #pragma unroll
            for (int c = 0; c < 8; ++c) a += dot8(wr[c], &s_vj[c * 8]);
            s_w[lane] = a + fn2b[lane];

            float m = 0.f;
            #pragma unroll
            for (int c = 0; c < 8; ++c){
                uint4 q = dr[c];
                const float* wp = &s_w[c * 8];
                m += fabsf(bflo(q.x) - wp[0]) + fabsf(bfhi(q.x) - wp[1])
                   + fabsf(bflo(q.y) - wp[2]) + fabsf(bfhi(q.y) - wp[3])
                   + fabsf(bflo(q.z) - wp[4]) + fabsf(bfhi(q.z) - wp[5])
                   + fabsf(bflo(q.w) - wp[6]) + fabsf(bfhi(q.w) - wp[7]);
            }
            s_M[lane] = -m;
        }
        __syncthreads();

        if (wv == 0){
            float e = s_scal;
            #pragma unroll
            for (int c = 0; c < 8; ++c) e += dot8(dr[c], &s_u[c * 8]);
            s_aij[lane] = tanhf(e) * sigm(s_M[lane] * mki + atti);
        }
        __syncthreads();
    }

    if (wv == 0)
        out[((size_t)n * NJ + j) * HO + lane] = s_vj[lane];
}

extern "C" void kernel_launch(void* const* d_in, const int* in_sizes, int n_in,
                              void* d_out, int out_size, void* d_ws, size_t ws_size,
                              hipStream_t stream)
{
    (void)in_sizes; (void)n_in; (void)out_size; (void)ws_size;
    const float* x      = (const float*)d_in[0];
    const float* mask   = (const float*)d_in[1];
    const float* Wcap   = (const float*)d_in[2];
    const float* Bcap   = (const float*)d_in[3];
    const float* Wv     = (const float*)d_in[4];
    const float* Bv     = (const float*)d_in[5];
    const float* scoreW = (const float*)d_in[6];
    const float* scoreb = (const float*)d_in[7];
    const float* alphaW = (const float*)d_in[8];
    const float* alphab = (const float*)d_in[9];
    const float* fe1W   = (const float*)d_in[10];
    const float* fe1b   = (const float*)d_in[11];
    const float* fe2W   = (const float*)d_in[12];
    const float* fe2b   = (const float*)d_in[13];
    const float* fn1W   = (const float*)d_in[14];
    const float* fn1b   = (const float*)d_in[15];
    const float* fn2W   = (const float*)d_in[16];
    const float* fn2b   = (const float*)d_in[17];
    const int*   itersp = (const int*)d_in[18];
    float* out = (float*)d_out;

    char* ws = (char*)d_ws;
    u16*   xcb   = (u16*)ws;                          //   4,194,304 B
    u16*   vts   = (u16*)(ws + 4194304);              //  67,108,864 B
    u16*   fnv   = (u16*)(ws + 71303168);             //  67,108,864 B
    float* bij   = (float*)(ws + 138412032);          //   2,097,152 B
    u16*   fn1wb = (u16*)(ws + 140509184);            //       8,192 B
    u16*   wAb   = (u16*)(ws + 140517376);            //       8,192 B
    u16*   wBb   = (u16*)(ws + 140525568);            //       8,192 B
    u16*   wCtb  = (u16*)(ws + 140533760);            //       8,192 B  (total ~140.5 MB)

    k_prep_small<<<1, 256, 0, stream>>>(fn1W, fe2W, fn2W, fe1W, fn1wb, wAb, wBb, wCtb);
    k_xc   <<<dim3(8, 64),     256, 0, stream>>>(x, Wcap, Bcap, xcb);
    k_votes<<<dim3(8, 16, 64), 256, 0, stream>>>(xcb, Wv, Bv, mask, fn1wb, fn1b,
                                                 scoreW, scoreb, vts, fnv, bij);
    k_route<<<8192,            128, 0, stream>>>(vts, fnv, bij, mask, alphaW, alphab,
                                                 wAb, fe2b, wBb, fn2b, wCtb, fe1b,
                                                 itersp, out);
}